// Round 16
// baseline (932.069 us; speedup 1.0000x reference)
//
#include <hip/hip_runtime.h>

typedef short short8 __attribute__((ext_vector_type(8)));
typedef float f4 __attribute__((ext_vector_type(4)));

#define BATCH 128
#define SEQ   512
#define EMB   256
#define HID   256
#define G4    1024   // 4*HID

static __device__ __forceinline__ unsigned short f2b(float f) {
    union { float f; unsigned int u; } v; v.f = f;
    unsigned int u = v.u;
    return (unsigned short)((u + 0x7FFFu + ((u >> 16) & 1u)) >> 16);  // RNE
}
static __device__ __forceinline__ float b2f(unsigned short s) {
    union { unsigned int u; float f; } v; v.u = ((unsigned int)s) << 16;
    return v.f;
}

// ---------------- Kernel 0: convert weights, fold biases, zero sync state -------
__global__ void prep_kernel(const float* __restrict__ W_x, const float* __restrict__ U_h,
                            const float* __restrict__ b_x, const float* __restrict__ b_u,
                            const float* __restrict__ b_g,
                            unsigned short* __restrict__ w_xb, unsigned short* __restrict__ u_hb,
                            float* __restrict__ bias,
                            unsigned int* __restrict__ hx32, float* __restrict__ out) {
    int i = blockIdx.x * blockDim.x + threadIdx.x;
    if (i < G4 * EMB) w_xb[i] = f2b(W_x[i]);
    if (i < G4 * HID) u_hb[i] = f2b(U_h[i]);
    if (i < G4) bias[i] = b_x[i] + b_u[i] + b_g[i];
    if (i < 65536) hx32[i] = 0;      // tag=0 everywhere (re-zeroed EVERY launch)
    if (i < 256) out[i] = 0.0f;      // out is atomicAdd-accumulated
}

// ---------------- Kernel 1: xp[s][b][g] = emb[tokens[b,s]] @ W_x^T + bias --------
__global__ __launch_bounds__(256) void xp_gemm(
    const int* __restrict__ tokens, const float* __restrict__ emb,
    const unsigned short* __restrict__ w_xb, const float* __restrict__ bias,
    unsigned short* __restrict__ xp)
{
    __shared__ unsigned short As[64][264];   // A tile
    __shared__ unsigned short Bs[64][264];   // staged B slice
    __shared__ unsigned short Xs[64][72];    // store-transpose bounce
    const int m0 = blockIdx.x * 64;
    const int b  = m0 >> 9;          // m0 / SEQ
    const int s0 = m0 & 511;         // m0 % SEQ
    const int tid = threadIdx.x;
    const int cS = tid >> 2, qS = (tid & 3) * 64;   // staging map (A and B)
    {
        const int tok = tokens[m0 + cS];
        const float* src = emb + (long)tok * EMB + qS;
        #pragma unroll
        for (int i = 0; i < 8; ++i) {
            float4 v0 = ((const float4*)src)[2 * i];
            float4 v1 = ((const float4*)src)[2 * i + 1];
            short8 pk;
            pk[0] = (short)f2b(v0.x); pk[1] = (short)f2b(v0.y);
            pk[2] = (short)f2b(v0.z); pk[3] = (short)f2b(v0.w);
            pk[4] = (short)f2b(v1.x); pk[5] = (short)f2b(v1.y);
            pk[6] = (short)f2b(v1.z); pk[7] = (short)f2b(v1.w);
            *(short8*)&As[cS][qS + i * 8] = pk;
        }
    }
    __syncthreads();
    const int w = tid >> 6, l = tid & 63;
    const int ln = l & 15, hi = l >> 4;
    short8 a[8];
    #pragma unroll
    for (int kk = 0; kk < 8; ++kk)
        a[kk] = *(const short8*)&As[16 * w + ln][kk * 32 + hi * 8];

    const int rl = tid >> 2;            // global-store row (own wave's rows)
    const int cl = (tid & 3) * 16;      // global-store col offset in 64-tile

    for (int n0 = 0; n0 < G4; n0 += 64) {
        {
            const unsigned short* src = &w_xb[(size_t)(n0 + cS) * EMB + qS];
            #pragma unroll
            for (int i = 0; i < 8; ++i)
                *(short8*)&Bs[cS][qS + i * 8] = *(const short8*)&src[i * 8];
        }
        __syncthreads();
        f4 acc[4] = {};
        #pragma unroll
        for (int kk = 0; kk < 8; ++kk) {
            #pragma unroll
            for (int nn = 0; nn < 4; ++nn) {
                short8 bfr = *(const short8*)&Bs[nn * 16 + ln][kk * 32 + hi * 8];
                acc[nn] = __builtin_amdgcn_mfma_f32_16x16x32_bf16(a[kk], bfr, acc[nn], 0, 0, 0);
            }
        }
        #pragma unroll
        for (int nn = 0; nn < 4; ++nn) {
            const float bs = bias[n0 + nn * 16 + ln];
            #pragma unroll
            for (int r = 0; r < 4; ++r)
                Xs[16 * w + 4 * hi + r][nn * 16 + ln] = f2b(acc[nn][r] + bs);
        }
        size_t off = ((size_t)(s0 + rl) * BATCH + b) * G4 + n0 + cl;
        *(short8*)&xp[off]     = *(const short8*)&Xs[rl][cl];
        *(short8*)&xp[off + 8] = *(const short8*)&Xs[rl][cl + 8];
        __syncthreads();
    }
}

// ---------------- Kernel 2: LSTM, 128 blocks = 8 groups x 16 sixteenths, 256 thr
// Block (g=bid&7, E=bid>>3): batch rows 16g..+16, units E*16..+16, all 4 gates.
// Swapped-operand MFMA, unit-major/gate-minor reorder => lane (w,hi,ln) owns the
// full cell (unit lu=w*4+hi, batch ln): acc[r] = gate r. Br[8] = 32 regs (AGPR).
// Wait precedes ALL MFMA (own units are half a slice - no pre-wait cover).
// Dual accumulators break the 8-deep MFMA chain (1 wave/SIMD has no overlap).
// Exchange: tagged-word protocol, 15 partners x 1 u32 poll/thread; parity dbuf.
// hxw layout: [2 par][8 g][16 E][256 cells], cell = lu*16 + batch.
__global__ void __launch_bounds__(256, 2)
lstm_recur(const unsigned short* __restrict__ xp,
           const unsigned short* __restrict__ u_hb,
           const float* __restrict__ fc_w, const float* __restrict__ fc_b,
           unsigned int* __restrict__ hxw, float* __restrict__ out)
{
    __shared__ unsigned short hsl0[4096];      // h slice-layout, parity 0: [8 s][512]
    __shared__ unsigned short hsl1[4096];      // parity 1
    __shared__ unsigned short xl0[16 * 68];    // xp tile [batch][4 gate][16 u], 68-pad
    __shared__ unsigned short xl1[16 * 68];
    const int tid = threadIdx.x;
    const int w = tid >> 6, l = tid & 63;
    const int ln = l & 15, hi = l >> 4;
    const int bid = blockIdx.x;
    const int g = bid & 7, E = bid >> 3;       // E in [0,16)
    const int lu = w * 4 + hi;                 // own unit within block [0,16)

    // A-frags: Br[s] = K-slice s (units 32s..32s+32), gu rows E*64 + w*16 + ln
    short8 Br[8];
    {
        const int col = (ln & 3) * 256 + E * 16 + w * 4 + (ln >> 2);
        const unsigned short* ubase = u_hb + (size_t)col * HID + hi * 8;
        #pragma unroll
        for (int s = 0; s < 8; ++s)
            Br[s] = *(const short8*)&ubase[s * 32];
    }

    // zero both h slice buffers (h(-1) = 0)
    for (int i = tid; i < 2048; i += 256) { ((unsigned*)hsl0)[i] = 0; ((unsigned*)hsl1)[i] = 0; }

    // xp staging: 1 u64 (4 us) per thread: row=tid>>4, seg=tid&15 (gate=seg>>2)
    const int xrow = tid >> 4, seg = tid & 15;
    const size_t xoff = (size_t)(16 * g + xrow) * 1024 + (seg >> 2) * 256 + E * 16 + (seg & 3) * 4;
    const int xdst = xrow * 68 + (seg >> 2) * 16 + (seg & 3) * 4;
    *(unsigned long long*)&xl0[xdst] = *(const unsigned long long*)(xp + xoff);
    __syncthreads();

    // ---- hoisted loop-invariant offsets ----
    int pbase[2], pub[2];
    #pragma unroll
    for (int par = 0; par < 2; ++par) {
        pbase[par] = (par * 8 + g) * 4096 + tid;            // poll: + pq*256
        pub[par]   = (par * 8 + g) * 4096 + E * 256 + lu * 16 + ln;
    }
    int ppq[15], sf[15];
    const int lup = tid >> 4, bp = tid & 15;   // import cell (unit lup of partner, batch bp)
    #pragma unroll
    for (int d = 0; d < 15; ++d) {
        const int pq = (E + 1 + d) & 15;
        ppq[d] = pq << 8;
        const int ug = pq * 16 + lup;
        const int ss = ug >> 5, k = ug & 31;
        sf[d] = ss * 512 + ((k >> 3) * 16 + bp) * 8 + (k & 7);
    }
    // own h dest + xp gate-read base
    const int ugo = E * 16 + lu;
    const int ko = ugo & 31;
    const int ho = (ugo >> 5) * 512 + ((ko >> 3) * 16 + ln) * 8 + (ko & 7);
    const int xb = ln * 68 + lu;
    const int fro = l * 8;

    float c0 = 0.0f;

    for (int t = 0; t < SEQ; ++t) {
        const int cur = t & 1;
        unsigned short* hslc = cur ? hsl1 : hsl0;    // h(t-1), frag layout
        unsigned short* hsln = cur ? hsl0 : hsl1;    // h(t) dest
        const unsigned short* xlc = cur ? xl1 : xl0;
        unsigned short* xln = cur ? xl0 : xl1;

        // issue 15 partner polls first (oldest in VMEM queue)
        unsigned int pw[15];
        const unsigned int* ps = hxw;
        if (t > 0) {
            ps = hxw + pbase[cur ^ 1];
            #pragma unroll
            for (int d = 0; d < 15; ++d)
                pw[d] = __hip_atomic_load(ps + ppq[d], __ATOMIC_RELAXED, __HIP_MEMORY_SCOPE_AGENT);
        }
        // prefetch next xp chunk
        unsigned long long sv;
        const bool do_stage = (t + 1 < SEQ);
        if (do_stage) sv = *(const unsigned long long*)(xp + (size_t)(t + 1) * 131072 + xoff);

        // wait for 15 partners; scatter their h into slice layout
        if (t > 0) {
            const unsigned int tag = (unsigned int)t;
            for (;;) {
                unsigned int bad = 0;
                #pragma unroll
                for (int d = 0; d < 15; ++d) bad |= (pw[d] ^ tag);
                if ((bad & 0xffffu) == 0u) break;
                #pragma unroll
                for (int d = 0; d < 15; ++d)
                    pw[d] = __hip_atomic_load(ps + ppq[d], __ATOMIC_RELAXED, __HIP_MEMORY_SCOPE_AGENT);
            }
            #pragma unroll
            for (int d = 0; d < 15; ++d)
                hslc[sf[d]] = (unsigned short)(pw[d] >> 16);
        }
        __syncthreads();

        // 8 slices MFMA, dual accumulator (break the dependency chain)
        f4 aa = {}, ab = {};
        #pragma unroll
        for (int s = 0; s < 8; s += 2) {
            short8 h0 = *(const short8*)&hslc[s * 512 + fro];
            short8 h1 = *(const short8*)&hslc[(s + 1) * 512 + fro];
            aa = __builtin_amdgcn_mfma_f32_16x16x32_bf16(Br[s], h0, aa, 0, 0, 0);
            ab = __builtin_amdgcn_mfma_f32_16x16x32_bf16(Br[s + 1], h1, ab, 0, 0, 0);
        }
        f4 acc = aa + ab;

        // gates: acc[r] = gate r of (unit lu, batch ln)
        float vf = acc[0] + b2f(xlc[xb]);
        float vi = acc[1] + b2f(xlc[xb + 16]);
        float vc = acc[2] + b2f(xlc[xb + 32]);
        float vo = acc[3] + b2f(xlc[xb + 48]);
        float ea = __expf(-vf), ei = __expf(-vi);
        float eb = __expf(-2.0f * vc), eo = __expf(-vo);
        float rf = __builtin_amdgcn_rcpf(1.0f + ea);
        float it = (1.0f - eb) * __builtin_amdgcn_rcpf((1.0f + ei) * (1.0f + eb));
        float cn = fmaf(rf, c0, it);
        c0 = cn;
        float ed = __expf(-2.0f * cn);
        float h = (1.0f - ed) * __builtin_amdgcn_rcpf((1.0f + eo) * (1.0f + ed));
        unsigned short hb16 = f2b(h);
        hsln[ho] = hb16;
        __hip_atomic_store(hxw + pub[cur], ((unsigned int)hb16 << 16) | (unsigned int)(t + 1),
                           __ATOMIC_RELAXED, __HIP_MEMORY_SCOPE_AGENT);

        // stage next xp tile (buffer not read this step)
        if (do_stage) *(unsigned long long*)&xln[xdst] = sv;
        __syncthreads();
    }

    // epilogue: own 16 units of h(511) live in hsl0 (t=511 wrote parity 0)
    if (tid < 32) {
        const int r = tid >> 1, o = tid & 1;
        float acc_fc = (E == 0) ? fc_b[o] : 0.0f;
        for (int jj = 0; jj < 16; ++jj) {
            const int ug = E * 16 + jj;
            const int k = ug & 31;
            float h = b2f(hsl0[(ug >> 5) * 512 + ((k >> 3) * 16 + r) * 8 + (k & 7)]);
            acc_fc += h * fc_w[o * HID + ug];
        }
        atomicAdd(&out[(16 * g + r) * 2 + o], acc_fc);
    }
}

extern "C" void kernel_launch(void* const* d_in, const int* in_sizes, int n_in,
                              void* d_out, int out_size, void* d_ws, size_t ws_size,
                              hipStream_t stream) {
    const int*   tokens = (const int*)  d_in[0];
    const float* emb    = (const float*)d_in[1];
    const float* W_x    = (const float*)d_in[2];
    const float* b_x    = (const float*)d_in[3];
    const float* U_h    = (const float*)d_in[4];
    const float* b_u    = (const float*)d_in[5];
    const float* b_g    = (const float*)d_in[6];
    const float* fc_w   = (const float*)d_in[7];
    const float* fc_b   = (const float*)d_in[8];
    float* out = (float*)d_out;

    char* ws = (char*)d_ws;
    unsigned short* w_xb  = (unsigned short*)(ws);                 // 512 KB
    unsigned short* u_hb  = (unsigned short*)(ws + 524288);        // 512 KB
    float*          bias  = (float*)(ws + 1048576);                // 4 KB
    unsigned int*   hxw   = (unsigned int*)(ws + 1052672);         // 256 KB [2][8][16][256] u32
    unsigned short* xp    = (unsigned short*)(ws + 1314816);       // 128 MB bf16 [S][B][4H]

    prep_kernel<<<1024, 256, 0, stream>>>(W_x, U_h, b_x, b_u, b_g, w_xb, u_hb, bias,
                                          hxw, out);
    xp_gemm<<<1024, 256, 0, stream>>>(tokens, emb, w_xb, bias, xp);

    lstm_recur<<<128, 256, 0, stream>>>(xp, u_hb, fc_w, fc_b, hxw, out);
}

// Round 17
// 721.847 us; speedup vs baseline: 1.2912x; 1.2912x over previous
//
#include <hip/hip_runtime.h>

typedef short short8 __attribute__((ext_vector_type(8)));
typedef float f4 __attribute__((ext_vector_type(4)));

#define BATCH 128
#define SEQ   512
#define EMB   256
#define HID   256
#define G4    1024   // 4*HID

static __device__ __forceinline__ unsigned short f2b(float f) {
    union { float f; unsigned int u; } v; v.f = f;
    unsigned int u = v.u;
    return (unsigned short)((u + 0x7FFFu + ((u >> 16) & 1u)) >> 16);  // RNE
}
static __device__ __forceinline__ float b2f(unsigned short s) {
    union { unsigned int u; float f; } v; v.u = ((unsigned int)s) << 16;
    return v.f;
}

// ---------------- Kernel 0: convert weights, fold biases, zero sync state -------
__global__ void prep_kernel(const float* __restrict__ W_x, const float* __restrict__ U_h,
                            const float* __restrict__ b_x, const float* __restrict__ b_u,
                            const float* __restrict__ b_g,
                            unsigned short* __restrict__ w_xb, unsigned short* __restrict__ u_hb,
                            float* __restrict__ bias,
                            unsigned int* __restrict__ hx32, float* __restrict__ out) {
    int i = blockIdx.x * blockDim.x + threadIdx.x;
    if (i < G4 * EMB) w_xb[i] = f2b(W_x[i]);
    if (i < G4 * HID) u_hb[i] = f2b(U_h[i]);
    if (i < G4) bias[i] = b_x[i] + b_u[i] + b_g[i];
    if (i < 65536) hx32[i] = 0;      // tag=0 everywhere (re-zeroed EVERY launch)
    if (i < 256) out[i] = 0.0f;      // out is atomicAdd-accumulated
}

// ---------------- Kernel 1: xp[s][b][g] = emb[tokens[b,s]] @ W_x^T + bias --------
// 128-row M-tiles (512 blocks): halves W_x L2/L3 re-read traffic vs 64-row.
// Dynamic LDS 119808 B: As[128][264] | Bs[64][264] | Xs[128][72].
__global__ __launch_bounds__(256) void xp_gemm(
    const int* __restrict__ tokens, const float* __restrict__ emb,
    const unsigned short* __restrict__ w_xb, const float* __restrict__ bias,
    unsigned short* __restrict__ xp)
{
    extern __shared__ unsigned short sm[];
    unsigned short* As = sm;                 // 128*264 us
    unsigned short* Bs = sm + 128 * 264;     // 64*264 us
    unsigned short* Xs = sm + 192 * 264;     // 128*72 us
    const int m0 = blockIdx.x * 128;
    const int b  = m0 >> 9;          // m0 / SEQ
    const int s0 = m0 & 511;         // m0 % SEQ (128 rows stay in one b)
    const int tid = threadIdx.x;
    // ---- stage A tile: row tid>>1, cols (tid&1)*128..+128 ----
    {
        const int r = tid >> 1, q = (tid & 1) * 128;
        const int tok = tokens[m0 + r];
        const float* src = emb + (long)tok * EMB + q;
        #pragma unroll
        for (int i = 0; i < 16; ++i) {
            float4 v0 = ((const float4*)src)[2 * i];
            float4 v1 = ((const float4*)src)[2 * i + 1];
            short8 pk;
            pk[0] = (short)f2b(v0.x); pk[1] = (short)f2b(v0.y);
            pk[2] = (short)f2b(v0.z); pk[3] = (short)f2b(v0.w);
            pk[4] = (short)f2b(v1.x); pk[5] = (short)f2b(v1.y);
            pk[6] = (short)f2b(v1.z); pk[7] = (short)f2b(v1.w);
            *(short8*)&As[r * 264 + q + i * 8] = pk;
        }
    }
    __syncthreads();
    const int w = tid >> 6, l = tid & 63;
    const int ln = l & 15, hi = l >> 4;
    // a-frags: wave w owns rows 32w..+32 = 2 M-tiles
    short8 a[2][8];
    #pragma unroll
    for (int mt = 0; mt < 2; ++mt)
        #pragma unroll
        for (int kk = 0; kk < 8; ++kk)
            a[mt][kk] = *(const short8*)&As[(32 * w + 16 * mt + ln) * 264 + kk * 32 + hi * 8];

    const int cB = tid >> 2, qB = (tid & 3) * 64;   // B staging map
    const int rl = tid >> 1, cl = (tid & 1) * 32;   // store map (same-wave rows)

    for (int n0 = 0; n0 < G4; n0 += 64) {
        // stage B slice: Bs[c][k] = w_xb[(n0+c)*256 + k]
        {
            const unsigned short* src = &w_xb[(size_t)(n0 + cB) * EMB + qB];
            #pragma unroll
            for (int i = 0; i < 8; ++i)
                *(short8*)&Bs[cB * 264 + qB + i * 8] = *(const short8*)&src[i * 8];
        }
        __syncthreads();
        f4 acc[2][4] = {};
        #pragma unroll
        for (int kk = 0; kk < 8; ++kk) {
            #pragma unroll
            for (int nn = 0; nn < 4; ++nn) {
                short8 bfr = *(const short8*)&Bs[(nn * 16 + ln) * 264 + kk * 32 + hi * 8];
                acc[0][nn] = __builtin_amdgcn_mfma_f32_16x16x32_bf16(a[0][kk], bfr, acc[0][nn], 0, 0, 0);
                acc[1][nn] = __builtin_amdgcn_mfma_f32_16x16x32_bf16(a[1][kk], bfr, acc[1][nn], 0, 0, 0);
            }
        }
        // bounce through LDS (wave-local rows: no barrier needed before read)
        #pragma unroll
        for (int mt = 0; mt < 2; ++mt)
            #pragma unroll
            for (int nn = 0; nn < 4; ++nn) {
                const float bs = bias[n0 + nn * 16 + ln];
                #pragma unroll
                for (int r = 0; r < 4; ++r)
                    Xs[(32 * w + 16 * mt + 4 * hi + r) * 72 + nn * 16 + ln] = f2b(acc[mt][nn][r] + bs);
            }
        size_t off = ((size_t)(s0 + rl) * BATCH + b) * G4 + n0 + cl;
        *(short8*)&xp[off]      = *(const short8*)&Xs[rl * 72 + cl];
        *(short8*)&xp[off + 8]  = *(const short8*)&Xs[rl * 72 + cl + 8];
        *(short8*)&xp[off + 16] = *(const short8*)&Xs[rl * 72 + cl + 16];
        *(short8*)&xp[off + 24] = *(const short8*)&Xs[rl * 72 + cl + 24];
        __syncthreads();   // protect Bs before next staging
    }
}

// ---------------- Kernel 2: LSTM, 64 blocks = 8 groups x 8 eighths, 512 thr -----
// (byte-identical revert to round-15's proven 556 us kernel)
// Block (g=bid&7, E=bid>>3): batch rows 16g..+16, units E*32..+32, all 4 gates.
// Swapped-operand MFMA, unit-major/gate-minor reorder => lane (w,hi,ln) owns the
// full cell (unit lu=w*4+hi, batch ln): acc[r] = gate r. Br[8] = 32 regs (AGPR).
// Exchange: tagged-word protocol, 7 partners x 1 u32 poll/thread; parity dbuf;
// publish-after-poll full graph => no ABA.
// hxw layout: [2 par][8 g][8 E][512 cells], cell = lu*16 + batch.
__global__ void __launch_bounds__(512, 2)
lstm_recur(const unsigned short* __restrict__ xp,
           const unsigned short* __restrict__ u_hb,
           const float* __restrict__ fc_w, const float* __restrict__ fc_b,
           unsigned int* __restrict__ hxw, float* __restrict__ out)
{
    __shared__ unsigned short hsl0[4096];      // h slice-layout, parity 0: [8 s][512]
    __shared__ unsigned short hsl1[4096];      // parity 1
    __shared__ unsigned short xl0[16 * 136];   // xp tile [batch][4 gate][32 u], 136-pad
    __shared__ unsigned short xl1[16 * 136];
    const int tid = threadIdx.x;
    const int w = tid >> 6, l = tid & 63;
    const int ln = l & 15, hi = l >> 4;
    const int bid = blockIdx.x;
    const int g = bid & 7, E = bid >> 3;
    const int lu = w * 4 + hi;                 // own unit within eighth [0,32)

    // A-frags, rotated slice order: Br[j] = slice (E+j)&7; own slice = j=0.
    short8 Br[8];
    int fo[8];
    {
        const int col = (ln & 3) * 256 + E * 32 + w * 4 + (ln >> 2);
        const unsigned short* ubase = u_hb + (size_t)col * HID + hi * 8;
        #pragma unroll
        for (int j = 0; j < 8; ++j) {
            const int s = (E + j) & 7;
            fo[j] = s * 512;
            Br[j] = *(const short8*)&ubase[s * 32];
        }
    }

    // zero both h slice buffers (h(-1) = 0)
    for (int i = tid; i < 2048; i += 512) { ((unsigned*)hsl0)[i] = 0; ((unsigned*)hsl1)[i] = 0; }

    // xp staging: 512 thr x 8 B: row=tid>>5, seg4=tid&31 (gate=seg4>>3, k=seg4&7)
    const int xrow = tid >> 5, seg4 = tid & 31;
    const size_t xoff = (size_t)(16 * g + xrow) * 1024 + (seg4 >> 3) * 256 + E * 32 + (seg4 & 7) * 4;
    const int xdst = xrow * 136 + (seg4 >> 3) * 32 + (seg4 & 7) * 4;
    *(unsigned long long*)&xl0[xdst] = *(const unsigned long long*)(xp + xoff);
    __syncthreads();

    // ---- hoisted loop-invariant offsets ----
    int pbase[2], pub[2];
    #pragma unroll
    for (int par = 0; par < 2; ++par) {
        pbase[par] = ((par * 8 + g) * 8) * 512 + tid;            // poll: + pq*512
        pub[par]   = ((par * 8 + g) * 8 + E) * 512 + lu * 16 + ln;
    }
    int ppq[7];
    #pragma unroll
    for (int d = 0; d < 7; ++d) ppq[d] = (((E + 1 + d) & 7) << 9);
    // scatter dest within partner slice region (import cell: lu'=tid>>4, b'=tid&15)
    const int lup = tid >> 4, bp = tid & 15;
    const int sbase = ((lup >> 3) * 16 + bp) * 8 + (lup & 7);
    // own h dest + xp gate-read base
    const int ho = E * 512 + ((lu >> 3) * 16 + ln) * 8 + (lu & 7);
    const int xb = ln * 136 + lu;
    const int fro = l * 8;

    float c0 = 0.0f;

    for (int t = 0; t < SEQ; ++t) {
        const int cur = t & 1;
        unsigned short* hslc = cur ? hsl1 : hsl0;    // h(t-1), frag layout
        unsigned short* hsln = cur ? hsl0 : hsl1;    // h(t) dest
        const unsigned short* xlc = cur ? xl1 : xl0;
        unsigned short* xln = cur ? xl0 : xl1;

        // issue 7 partner polls first (oldest in VMEM queue)
        unsigned int pw[7];
        const unsigned int* ps = hxw;
        if (t > 0) {
            ps = hxw + pbase[cur ^ 1];
            #pragma unroll
            for (int d = 0; d < 7; ++d)
                pw[d] = __hip_atomic_load(ps + ppq[d], __ATOMIC_RELAXED, __HIP_MEMORY_SCOPE_AGENT);
        }
        // prefetch next xp chunk
        unsigned long long sv;
        const bool do_stage = (t + 1 < SEQ);
        if (do_stage) sv = *(const unsigned long long*)(xp + (size_t)(t + 1) * 131072 + xoff);

        // own slice (j=0): own-eighth h written by us last step
        f4 acc = {};
        {
            short8 hf = *(const short8*)&hslc[fo[0] + fro];
            acc = __builtin_amdgcn_mfma_f32_16x16x32_bf16(Br[0], hf, acc, 0, 0, 0);
        }

        // wait for 7 partners; scatter their h into slice layout
        if (t > 0) {
            const unsigned int tag = (unsigned int)t;
            for (;;) {
                unsigned int bad = 0;
                #pragma unroll
                for (int d = 0; d < 7; ++d) bad |= (pw[d] ^ tag);
                if ((bad & 0xffffu) == 0u) break;
                #pragma unroll
                for (int d = 0; d < 7; ++d)
                    pw[d] = __hip_atomic_load(ps + ppq[d], __ATOMIC_RELAXED, __HIP_MEMORY_SCOPE_AGENT);
            }
            #pragma unroll
            for (int d = 0; d < 7; ++d)
                hslc[ppq[d] + sbase] = (unsigned short)(pw[d] >> 16);
        }
        __syncthreads();

        // partner slices j=1..7
        #pragma unroll
        for (int j = 1; j < 8; ++j) {
            short8 hf = *(const short8*)&hslc[fo[j] + fro];
            acc = __builtin_amdgcn_mfma_f32_16x16x32_bf16(Br[j], hf, acc, 0, 0, 0);
        }

        // gates: acc[r] = gate r of (unit lu, batch ln)
        float vf = acc[0] + b2f(xlc[xb]);
        float vi = acc[1] + b2f(xlc[xb + 32]);
        float vc = acc[2] + b2f(xlc[xb + 64]);
        float vo = acc[3] + b2f(xlc[xb + 96]);
        float ea = __expf(-vf), ei = __expf(-vi);
        float eb = __expf(-2.0f * vc), eo = __expf(-vo);
        float rf = __builtin_amdgcn_rcpf(1.0f + ea);
        float it = (1.0f - eb) * __builtin_amdgcn_rcpf((1.0f + ei) * (1.0f + eb));
        float cn = fmaf(rf, c0, it);
        c0 = cn;
        float ed = __expf(-2.0f * cn);
        float h = (1.0f - ed) * __builtin_amdgcn_rcpf((1.0f + eo) * (1.0f + ed));
        unsigned short hb16 = f2b(h);
        hsln[ho] = hb16;
        __hip_atomic_store(hxw + pub[cur], ((unsigned int)hb16 << 16) | (unsigned int)(t + 1),
                           __ATOMIC_RELAXED, __HIP_MEMORY_SCOPE_AGENT);

        // stage next xp tile (buffer not read this step)
        if (do_stage) *(unsigned long long*)&xln[xdst] = sv;
        __syncthreads();
    }

    // epilogue: own 32 units of h(511) live in hsl0 (t=511 wrote parity 0)
    if (tid < 32) {
        const int r = tid >> 1, o = tid & 1;
        float acc_fc = (E == 0) ? fc_b[o] : 0.0f;
        for (int jj = 0; jj < 32; ++jj) {
            float h = b2f(hsl0[E * 512 + ((jj >> 3) * 16 + r) * 8 + (jj & 7)]);
            acc_fc += h * fc_w[o * HID + E * 32 + jj];
        }
        atomicAdd(&out[(16 * g + r) * 2 + o], acc_fc);
    }
}

extern "C" void kernel_launch(void* const* d_in, const int* in_sizes, int n_in,
                              void* d_out, int out_size, void* d_ws, size_t ws_size,
                              hipStream_t stream) {
    const int*   tokens = (const int*)  d_in[0];
    const float* emb    = (const float*)d_in[1];
    const float* W_x    = (const float*)d_in[2];
    const float* b_x    = (const float*)d_in[3];
    const float* U_h    = (const float*)d_in[4];
    const float* b_u    = (const float*)d_in[5];
    const float* b_g    = (const float*)d_in[6];
    const float* fc_w   = (const float*)d_in[7];
    const float* fc_b   = (const float*)d_in[8];
    float* out = (float*)d_out;

    char* ws = (char*)d_ws;
    unsigned short* w_xb  = (unsigned short*)(ws);                 // 512 KB
    unsigned short* u_hb  = (unsigned short*)(ws + 524288);        // 512 KB
    float*          bias  = (float*)(ws + 1048576);                // 4 KB
    unsigned int*   hxw   = (unsigned int*)(ws + 1052672);         // 256 KB [2][8][8][512] u32
    unsigned short* xp    = (unsigned short*)(ws + 1314816);       // 128 MB bf16 [S][B][4H]

    prep_kernel<<<1024, 256, 0, stream>>>(W_x, U_h, b_x, b_u, b_g, w_xb, u_hb, bias,
                                          hxw, out);
    (void)hipFuncSetAttribute((const void*)xp_gemm,
                              hipFuncAttributeMaxDynamicSharedMemorySize, 119808);
    xp_gemm<<<512, 256, 119808, stream>>>(tokens, emb, w_xb, bias, xp);

    lstm_recur<<<64, 512, 0, stream>>>(xp, u_hb, fc_w, fc_b, hxw, out);
}

// Round 18
// 663.056 us; speedup vs baseline: 1.4057x; 1.0887x over previous
//
#include <hip/hip_runtime.h>

typedef short short8 __attribute__((ext_vector_type(8)));
typedef float f4 __attribute__((ext_vector_type(4)));

#define BATCH 128
#define SEQ   512
#define EMB   256
#define HID   256
#define G4    1024   // 4*HID

static __device__ __forceinline__ unsigned short f2b(float f) {
    union { float f; unsigned int u; } v; v.f = f;
    unsigned int u = v.u;
    return (unsigned short)((u + 0x7FFFu + ((u >> 16) & 1u)) >> 16);  // RNE
}
static __device__ __forceinline__ float b2f(unsigned short s) {
    union { unsigned int u; float f; } v; v.u = ((unsigned int)s) << 16;
    return v.f;
}

// ---------------- Kernel 0: convert weights, fold biases, zero sync state -------
__global__ void prep_kernel(const float* __restrict__ W_x, const float* __restrict__ U_h,
                            const float* __restrict__ b_x, const float* __restrict__ b_u,
                            const float* __restrict__ b_g,
                            unsigned short* __restrict__ w_xb, unsigned short* __restrict__ u_hb,
                            float* __restrict__ bias,
                            unsigned int* __restrict__ hx32, float* __restrict__ out) {
    int i = blockIdx.x * blockDim.x + threadIdx.x;
    if (i < G4 * EMB) w_xb[i] = f2b(W_x[i]);
    if (i < G4 * HID) u_hb[i] = f2b(U_h[i]);
    if (i < G4) bias[i] = b_x[i] + b_u[i] + b_g[i];
    if (i < 65536) hx32[i] = 0;      // tag=0 everywhere (re-zeroed EVERY launch)
    if (i < 256) out[i] = 0.0f;      // out is atomicAdd-accumulated
}

// ---------------- Kernel 1: xp[s][b][g] = emb[tokens[b,s]] @ W_x^T + bias --------
__global__ __launch_bounds__(256) void xp_gemm(
    const int* __restrict__ tokens, const float* __restrict__ emb,
    const unsigned short* __restrict__ w_xb, const float* __restrict__ bias,
    unsigned short* __restrict__ xp)
{
    __shared__ unsigned short As[64][264];   // A tile
    __shared__ unsigned short Bs[64][264];   // staged B slice
    __shared__ unsigned short Xs[64][72];    // store-transpose bounce
    const int m0 = blockIdx.x * 64;
    const int b  = m0 >> 9;          // m0 / SEQ
    const int s0 = m0 & 511;         // m0 % SEQ
    const int tid = threadIdx.x;
    const int cS = tid >> 2, qS = (tid & 3) * 64;   // staging map (A and B)
    {
        const int tok = tokens[m0 + cS];
        const float* src = emb + (long)tok * EMB + qS;
        #pragma unroll
        for (int i = 0; i < 8; ++i) {
            float4 v0 = ((const float4*)src)[2 * i];
            float4 v1 = ((const float4*)src)[2 * i + 1];
            short8 pk;
            pk[0] = (short)f2b(v0.x); pk[1] = (short)f2b(v0.y);
            pk[2] = (short)f2b(v0.z); pk[3] = (short)f2b(v0.w);
            pk[4] = (short)f2b(v1.x); pk[5] = (short)f2b(v1.y);
            pk[6] = (short)f2b(v1.z); pk[7] = (short)f2b(v1.w);
            *(short8*)&As[cS][qS + i * 8] = pk;
        }
    }
    __syncthreads();
    const int w = tid >> 6, l = tid & 63;
    const int ln = l & 15, hi = l >> 4;
    short8 a[8];
    #pragma unroll
    for (int kk = 0; kk < 8; ++kk)
        a[kk] = *(const short8*)&As[16 * w + ln][kk * 32 + hi * 8];

    const int rl = tid >> 2;            // global-store row (own wave's rows)
    const int cl = (tid & 3) * 16;      // global-store col offset in 64-tile

    for (int n0 = 0; n0 < G4; n0 += 64) {
        {
            const unsigned short* src = &w_xb[(size_t)(n0 + cS) * EMB + qS];
            #pragma unroll
            for (int i = 0; i < 8; ++i)
                *(short8*)&Bs[cS][qS + i * 8] = *(const short8*)&src[i * 8];
        }
        __syncthreads();
        f4 acc[4] = {};
        #pragma unroll
        for (int kk = 0; kk < 8; ++kk) {
            #pragma unroll
            for (int nn = 0; nn < 4; ++nn) {
                short8 bfr = *(const short8*)&Bs[nn * 16 + ln][kk * 32 + hi * 8];
                acc[nn] = __builtin_amdgcn_mfma_f32_16x16x32_bf16(a[kk], bfr, acc[nn], 0, 0, 0);
            }
        }
        #pragma unroll
        for (int nn = 0; nn < 4; ++nn) {
            const float bs = bias[n0 + nn * 16 + ln];
            #pragma unroll
            for (int r = 0; r < 4; ++r)
                Xs[16 * w + 4 * hi + r][nn * 16 + ln] = f2b(acc[nn][r] + bs);
        }
        size_t off = ((size_t)(s0 + rl) * BATCH + b) * G4 + n0 + cl;
        *(short8*)&xp[off]     = *(const short8*)&Xs[rl][cl];
        *(short8*)&xp[off + 8] = *(const short8*)&Xs[rl][cl + 8];
        __syncthreads();
    }
}

// ---------------- Kernel 2: LSTM, 64 blocks = 8 groups x 8 eighths, 512 thr -----
// Block (g=bid&7, E=bid>>3): batch rows 16g..+16, units E*32..+32, all 4 gates.
// Swapped-operand MFMA, unit-major/gate-minor reorder => lane (w,hi,ln) owns the
// full cell (unit lu=w*4+hi, batch ln): acc[r] = gate r. Br[8] = 32 regs (AGPR).
// Exchange: tagged-word protocol, 7 partners x 1 u32 poll/thread; parity dbuf;
// publish-after-poll full graph => no ABA.
// hxw layout: [2 par][8 g][8 E][512 cells], cell = lu*16 + batch.
__global__ void __launch_bounds__(512, 2)
lstm_recur(const unsigned short* __restrict__ xp,
           const unsigned short* __restrict__ u_hb,
           const float* __restrict__ fc_w, const float* __restrict__ fc_b,
           unsigned int* __restrict__ hxw, float* __restrict__ out)
{
    __shared__ unsigned short hsl0[4096];      // h slice-layout, parity 0: [8 s][512]
    __shared__ unsigned short hsl1[4096];      // parity 1
    __shared__ unsigned short xl0[16 * 136];   // xp tile [batch][4 gate][32 u], 136-pad
    __shared__ unsigned short xl1[16 * 136];
    const int tid = threadIdx.x;
    const int w = tid >> 6, l = tid & 63;
    const int ln = l & 15, hi = l >> 4;
    const int bid = blockIdx.x;
    const int g = bid & 7, E = bid >> 3;
    const int lu = w * 4 + hi;                 // own unit within eighth [0,32)

    // A-frags, rotated slice order: Br[j] = slice (E+j)&7; own slice = j=0.
    short8 Br[8];
    int fo[8];
    {
        const int col = (ln & 3) * 256 + E * 32 + w * 4 + (ln >> 2);
        const unsigned short* ubase = u_hb + (size_t)col * HID + hi * 8;
        #pragma unroll
        for (int j = 0; j < 8; ++j) {
            const int s = (E + j) & 7;
            fo[j] = s * 512;
            Br[j] = *(const short8*)&ubase[s * 32];
        }
    }

    // zero both h slice buffers (h(-1) = 0)
    for (int i = tid; i < 2048; i += 512) { ((unsigned*)hsl0)[i] = 0; ((unsigned*)hsl1)[i] = 0; }

    // xp staging: 512 thr x 8 B: row=tid>>5, seg4=tid&31 (gate=seg4>>3, k=seg4&7)
    const int xrow = tid >> 5, seg4 = tid & 31;
    const size_t xoff = (size_t)(16 * g + xrow) * 1024 + (seg4 >> 3) * 256 + E * 32 + (seg4 & 7) * 4;
    const int xdst = xrow * 136 + (seg4 >> 3) * 32 + (seg4 & 7) * 4;
    *(unsigned long long*)&xl0[xdst] = *(const unsigned long long*)(xp + xoff);
    __syncthreads();

    // ---- hoisted loop-invariant offsets ----
    int pbase[2], pub[2];
    #pragma unroll
    for (int par = 0; par < 2; ++par) {
        pbase[par] = ((par * 8 + g) * 8) * 512 + tid;            // poll: + pq*512
        pub[par]   = ((par * 8 + g) * 8 + E) * 512 + lu * 16 + ln;
    }
    int ppq[7];
    #pragma unroll
    for (int d = 0; d < 7; ++d) ppq[d] = (((E + 1 + d) & 7) << 9);
    // scatter dest within partner slice region (import cell: lu'=tid>>4, b'=tid&15)
    const int lup = tid >> 4, bp = tid & 15;
    const int sbase = ((lup >> 3) * 16 + bp) * 8 + (lup & 7);
    // own h dest + xp gate-read base
    const int ho = E * 512 + ((lu >> 3) * 16 + ln) * 8 + (lu & 7);
    const int xb = ln * 136 + lu;
    const int fro = l * 8;

    float c0 = 0.0f;

    for (int t = 0; t < SEQ; ++t) {
        const int cur = t & 1;
        unsigned short* hslc = cur ? hsl1 : hsl0;    // h(t-1), frag layout
        unsigned short* hsln = cur ? hsl0 : hsl1;    // h(t) dest
        const unsigned short* xlc = cur ? xl1 : xl0;
        unsigned short* xln = cur ? xl0 : xl1;

        // issue 7 partner polls first (oldest in VMEM queue)
        unsigned int pw[7];
        const unsigned int* ps = hxw;
        if (t > 0) {
            ps = hxw + pbase[cur ^ 1];
            #pragma unroll
            for (int d = 0; d < 7; ++d)
                pw[d] = __hip_atomic_load(ps + ppq[d], __ATOMIC_RELAXED, __HIP_MEMORY_SCOPE_AGENT);
        }
        // prefetch next xp chunk
        unsigned long long sv;
        const bool do_stage = (t + 1 < SEQ);
        if (do_stage) sv = *(const unsigned long long*)(xp + (size_t)(t + 1) * 131072 + xoff);

        // own slice (j=0): own-eighth h written by us last step
        f4 acc = {};
        {
            short8 hf = *(const short8*)&hslc[fo[0] + fro];
            acc = __builtin_amdgcn_mfma_f32_16x16x32_bf16(Br[0], hf, acc, 0, 0, 0);
        }

        // wait for 7 partners; scatter their h into slice layout
        if (t > 0) {
            const unsigned int tag = (unsigned int)t;
            for (;;) {
                unsigned int bad = 0;
                #pragma unroll
                for (int d = 0; d < 7; ++d) bad |= (pw[d] ^ tag);
                if ((bad & 0xffffu) == 0u) break;
                #pragma unroll
                for (int d = 0; d < 7; ++d)
                    pw[d] = __hip_atomic_load(ps + ppq[d], __ATOMIC_RELAXED, __HIP_MEMORY_SCOPE_AGENT);
            }
            #pragma unroll
            for (int d = 0; d < 7; ++d)
                hslc[ppq[d] + sbase] = (unsigned short)(pw[d] >> 16);
        }
        __syncthreads();

        // partner slices j=1..7
        #pragma unroll
        for (int j = 1; j < 8; ++j) {
            short8 hf = *(const short8*)&hslc[fo[j] + fro];
            acc = __builtin_amdgcn_mfma_f32_16x16x32_bf16(Br[j], hf, acc, 0, 0, 0);
        }

        // gates: acc[r] = gate r of (unit lu, batch ln)
        float vf = acc[0] + b2f(xlc[xb]);
        float vi = acc[1] + b2f(xlc[xb + 32]);
        float vc = acc[2] + b2f(xlc[xb + 64]);
        float vo = acc[3] + b2f(xlc[xb + 96]);
        float ea = __expf(-vf), ei = __expf(-vi);
        float eb = __expf(-2.0f * vc), eo = __expf(-vo);
        float rf = __builtin_amdgcn_rcpf(1.0f + ea);
        float it = (1.0f - eb) * __builtin_amdgcn_rcpf((1.0f + ei) * (1.0f + eb));
        float cn = fmaf(rf, c0, it);
        c0 = cn;
        float ed = __expf(-2.0f * cn);
        float h = (1.0f - ed) * __builtin_amdgcn_rcpf((1.0f + eo) * (1.0f + ed));
        unsigned short hb16 = f2b(h);
        hsln[ho] = hb16;
        __hip_atomic_store(hxw + pub[cur], ((unsigned int)hb16 << 16) | (unsigned int)(t + 1),
                           __ATOMIC_RELAXED, __HIP_MEMORY_SCOPE_AGENT);

        // stage next xp tile (buffer not read this step)
        if (do_stage) *(unsigned long long*)&xln[xdst] = sv;
        __syncthreads();
    }

    // epilogue: own 32 units of h(511) live in hsl0 (t=511 wrote parity 0)
    if (tid < 32) {
        const int r = tid >> 1, o = tid & 1;
        float acc_fc = (E == 0) ? fc_b[o] : 0.0f;
        for (int jj = 0; jj < 32; ++jj) {
            float h = b2f(hsl0[E * 512 + ((jj >> 3) * 16 + r) * 8 + (jj & 7)]);
            acc_fc += h * fc_w[o * HID + E * 32 + jj];
        }
        atomicAdd(&out[(16 * g + r) * 2 + o], acc_fc);
    }
}

extern "C" void kernel_launch(void* const* d_in, const int* in_sizes, int n_in,
                              void* d_out, int out_size, void* d_ws, size_t ws_size,
                              hipStream_t stream) {
    const int*   tokens = (const int*)  d_in[0];
    const float* emb    = (const float*)d_in[1];
    const float* W_x    = (const float*)d_in[2];
    const float* b_x    = (const float*)d_in[3];
    const float* U_h    = (const float*)d_in[4];
    const float* b_u    = (const float*)d_in[5];
    const float* b_g    = (const float*)d_in[6];
    const float* fc_w   = (const float*)d_in[7];
    const float* fc_b   = (const float*)d_in[8];
    float* out = (float*)d_out;

    char* ws = (char*)d_ws;
    unsigned short* w_xb  = (unsigned short*)(ws);                 // 512 KB
    unsigned short* u_hb  = (unsigned short*)(ws + 524288);        // 512 KB
    float*          bias  = (float*)(ws + 1048576);                // 4 KB
    unsigned int*   hxw   = (unsigned int*)(ws + 1052672);         // 256 KB [2][8][8][512] u32
    unsigned short* xp    = (unsigned short*)(ws + 1314816);       // 128 MB bf16 [S][B][4H]

    prep_kernel<<<1024, 256, 0, stream>>>(W_x, U_h, b_x, b_u, b_g, w_xb, u_hb, bias,
                                          hxw, out);
    xp_gemm<<<1024, 256, 0, stream>>>(tokens, emb, w_xb, bias, xp);

    lstm_recur<<<64, 512, 0, stream>>>(xp, u_hb, fc_w, fc_b, hxw, out);
}